// Round 1
// baseline (176.776 us; speedup 1.0000x reference)
//
#include <hip/hip_runtime.h>
#include <math.h>

#define HH 1080
#define WW 1920
#define RAD 5
#define TX 32
#define TY 32
#define RPT 4
#define BDY 8
#define LR (TY + 2*RAD)   // 42
#define LC (TX + 2*RAD)   // 42

__device__ __forceinline__ float fast_rcp(float x) {
#if __has_builtin(__builtin_amdgcn_rcpf)
    return __builtin_amdgcn_rcpf(x);
#else
    return 1.0f / x;
#endif
}
__device__ __forceinline__ float fast_rsq(float x) {
#if __has_builtin(__builtin_amdgcn_rsqf)
    return __builtin_amdgcn_rsqf(x);
#else
    return rsqrtf(x);
#endif
}
__device__ __forceinline__ float fast_log2(float x) {
#if __has_builtin(__builtin_amdgcn_logf)
    return __builtin_amdgcn_logf(x);
#else
    return __log2f(x);
#endif
}
__device__ __forceinline__ float fast_exp2(float x) {
#if __has_builtin(__builtin_amdgcn_exp2f)
    return __builtin_amdgcn_exp2f(x);
#else
    return exp2f(x);
#endif
}
__device__ __forceinline__ float fast_sqrt(float x) {
#if __has_builtin(__builtin_amdgcn_sqrtf)
    return __builtin_amdgcn_sqrtf(x);
#else
    return sqrtf(x);
#endif
}

// Weight: w = exp(-d2/8) * clip(dot,0,1)^128 * exp(-|tz-z| / max(dz*sqrt(d2), 1e-4))
// Fused: w = exp2( -d2*0.18033688 + 128*log2(max(dot,0)) - log2e*|tz-z|*rcp(max(dz*sqrt(d2),1e-4)) )
// (upper clip at 1 skipped: dot <= 1 + few-ulp for unit vectors -> ^128 error ~1e-5, far below 2e-2 threshold;
//  dot<=0 or zero-padded halo normals give log2(0) = -inf -> w = 0, which reproduces the reference mask t_m)

__global__ __launch_bounds__(TX*BDY, 2)
void denoise_kernel(const float* __restrict__ in, float* __restrict__ out) {
    __shared__ float4 sA[LR][LC];   // c0,c1,c2,n0
    __shared__ float4 sB[LR][LC];   // n1,n2,z,dz

    const int tx = threadIdx.x;
    const int ty = threadIdx.y;
    const int tid = ty * TX + tx;
    const int x0 = blockIdx.x * TX;
    const int y0 = blockIdx.y * TY;

    // ---- stage tile + halo into LDS, normalizing normals on the fly ----
    #pragma unroll
    for (int i = 0; i < (LR*LC + TX*BDY - 1) / (TX*BDY); ++i) {
        int idx = tid + i * (TX*BDY);
        if (idx < LR*LC) {
            int r = idx / LC, c = idx % LC;
            int gx = x0 + c - RAD;
            int gy = y0 + r - RAD;
            float4 a = make_float4(0.f, 0.f, 0.f, 0.f);
            float4 b = make_float4(0.f, 0.f, 0.f, 0.f);
            if (gx >= 0 && gx < WW && gy >= 0 && gy < HH) {
                const float4* p = reinterpret_cast<const float4*>(in + ((size_t)gy * WW + gx) * 8);
                a = p[0];
                b = p[1];
            }
            float nn = a.w * a.w + b.x * b.x + b.y * b.y;
            float s = fast_rsq(fmaxf(nn, 1e-20f));
            a.w *= s; b.x *= s; b.y *= s;
            sA[r][c] = a;
            sB[r][c] = b;
        }
    }
    __syncthreads();

    // ---- per-thread centers (4 vertically adjacent output pixels) ----
    float cn0[RPT], cn1[RPT], cn2[RPT], cz[RPT], cdz[RPT];
    #pragma unroll
    for (int o = 0; o < RPT; ++o) {
        float4 A = sA[ty * RPT + RAD + o][tx + RAD];
        float4 B = sB[ty * RPT + RAD + o][tx + RAD];
        cn0[o] = A.w; cn1[o] = B.x; cn2[o] = B.y; cz[o] = B.z; cdz[o] = B.w;
    }

    float accx[RPT] = {0.f, 0.f, 0.f, 0.f};
    float accy[RPT] = {0.f, 0.f, 0.f, 0.f};
    float accz[RPT] = {0.f, 0.f, 0.f, 0.f};
    float accw[RPT] = {0.f, 0.f, 0.f, 0.f};

    // ---- main tap loop: 14 rows, each tap read once, used by up to 4 outputs ----
    for (int r = 0; r < 2 * RAD + RPT; ++r) {
        float dy2[RPT];
        bool  val[RPT];
        #pragma unroll
        for (int o = 0; o < RPT; ++o) {
            int dy = r - RAD - o;           // tap row offset relative to output o
            val[o] = (dy >= -RAD) && (dy <= RAD);
            float d = (float)dy;
            dy2[o] = d * d;
        }
        #pragma unroll
        for (int dx = 0; dx < 2 * RAD + 1; ++dx) {
            float4 A = sA[ty * RPT + r][tx + dx];
            float4 B = sB[ty * RPT + r][tx + dx];
            const float dxf  = (float)(dx - RAD);
            const float dx2c = dxf * dxf;
            #pragma unroll
            for (int o = 0; o < RPT; ++o) {
                if (val[o]) {
                    float d2   = dy2[o] + dx2c;
                    float sd2  = fast_sqrt(d2);
                    float cxy  = d2 * -0.18033688011112042f;        // -d2/8 * log2(e)
                    float dot  = A.w * cn0[o] + B.x * cn1[o] + B.y * cn2[o];
                    float wn   = fmaxf(dot, 0.0f);
                    float lg   = fast_log2(wn);                      // -inf at 0 -> w=0
                    float eb   = fmaf(lg, 128.0f, cxy);
                    float den  = fmaxf(cdz[o] * sd2, 1e-4f);
                    float u    = fabsf(B.z - cz[o]) * fast_rcp(den);
                    float e2   = fmaf(u, -1.4426950408889634f, eb);
                    float w    = fast_exp2(e2);
                    accx[o] = fmaf(A.x, w, accx[o]);
                    accy[o] = fmaf(A.y, w, accy[o]);
                    accz[o] = fmaf(A.z, w, accz[o]);
                    accw[o] += w;
                }
            }
        }
    }

    // ---- epilogue: divide and store ----
    const int xo = x0 + tx;
    #pragma unroll
    for (int o = 0; o < RPT; ++o) {
        int y = y0 + ty * RPT + o;
        if (y < HH) {
            float inv = 1.0f / accw[o];
            size_t base = ((size_t)y * WW + xo) * 3;
            out[base + 0] = accx[o] * inv;
            out[base + 1] = accy[o] * inv;
            out[base + 2] = accz[o] * inv;
        }
    }
}

extern "C" void kernel_launch(void* const* d_in, const int* in_sizes, int n_in,
                              void* d_out, int out_size, void* d_ws, size_t ws_size,
                              hipStream_t stream) {
    const float* in = (const float*)d_in[0];
    float* out = (float*)d_out;
    dim3 grid((WW + TX - 1) / TX, (HH + TY - 1) / TY);   // 60 x 34
    dim3 block(TX, BDY);                                  // 256 threads
    hipLaunchKernelGGL(denoise_kernel, grid, block, 0, stream, in, out);
}